// Round 8
// baseline (250.810 us; speedup 1.0000x reference)
//
#include <hip/hip_runtime.h>

#define BB 2
#define SS 2048
#define EE 1024
#define HH 16
#define DD_ 64
#define BH (BB*HH)
#define NQKV (3*EE)
#define MROWS (BB*SS)

typedef _Float16 f16;
typedef _Float16 f16x8 __attribute__((ext_vector_type(8)));
typedef _Float16 f16x4 __attribute__((ext_vector_type(4)));
typedef __fp16 fp16x2 __attribute__((ext_vector_type(2)));
typedef float f32x4 __attribute__((ext_vector_type(4)));
typedef float f32x16 __attribute__((ext_vector_type(16)));

#define MFMA16(a,b,c) __builtin_amdgcn_mfma_f32_16x16x32_f16(a,b,c,0,0,0)
#define MFMA32(a,b,c) __builtin_amdgcn_mfma_f32_32x32x16_f16(a,b,c,0,0,0)
#define EXP2F(x) __builtin_amdgcn_exp2f(x)
#define LOG2E 1.44269504088896f

__device__ __forceinline__ void gload16(const void* g, void* l) {
    __builtin_amdgcn_global_load_lds(
        (const __attribute__((address_space(1))) void*)g,
        (__attribute__((address_space(3))) void*)l, 16, 0, 0);
}

// ---------------------------------------------------------------------------
// fp32 -> f16 one-shot convert: x (4M), qkv_w (3M), out_w (1M) floats.
// ---------------------------------------------------------------------------
#define NX4  1048576
#define NW14  786432
#define NW24  262144
__global__ __launch_bounds__(256) void cvt_kernel(
    const float* __restrict__ x, const float* __restrict__ w1,
    const float* __restrict__ w2, f16* __restrict__ x16,
    f16* __restrict__ w116, f16* __restrict__ w216)
{
    const int i = blockIdx.x * 256 + threadIdx.x;
    const float* src; f16* dst; int off;
    if (i < NX4)              { src = x;  dst = x16;  off = i; }
    else if (i < NX4 + NW14)  { src = w1; dst = w116; off = i - NX4; }
    else                      { src = w2; dst = w216; off = i - NX4 - NW14; }
    float4 v = ((const float4*)src)[off];
    f16x4 h = { (f16)v.x, (f16)v.y, (f16)v.z, (f16)v.w };
    *(f16x4*)(dst + 4*(size_t)off) = h;
}

// ---------------------------------------------------------------------------
// QKV GEMM, f16 MFMA 16x16x32, 128x128 tile, BK=64, 4 waves.
// ---------------------------------------------------------------------------
__global__ __launch_bounds__(256) void qkv_gemm_kernel(
    const f16* __restrict__ x, const f16* __restrict__ w,
    const float* __restrict__ bias, const float* __restrict__ gates,
    const float* __restrict__ imp, const float* __restrict__ thr,
    f16* __restrict__ q16, f16* __restrict__ k16, f16* __restrict__ v16)
{
    __shared__ f16 As[128*64];
    __shared__ f16 Bs[128*64];
    const int tid  = threadIdx.x;
    const int wave = tid >> 6, lane = tid & 63;
    const int quad = lane >> 4, l15 = lane & 15;
    const int wm = wave & 1, wn = wave >> 1;
    const int m0 = blockIdx.y << 7, n0 = blockIdx.x << 7;

    f32x4 acc[4][4];
#pragma unroll
    for (int i = 0; i < 4; ++i)
#pragma unroll
        for (int j = 0; j < 4; ++j) acc[i][j] = (f32x4){0.f,0.f,0.f,0.f};

    for (int k0 = 0; k0 < EE; k0 += 64) {
        __syncthreads();
#pragma unroll
        for (int u = 0; u < 4; ++u) {
            const int s = tid + (u << 8);
            const int r = s >> 3;
            const int sc = ((s & 7) ^ (r & 7)) << 3;
            gload16(x + (size_t)(m0 + r)*EE + k0 + sc, &As[s << 3]);
            gload16(w + (size_t)(n0 + r)*EE + k0 + sc, &Bs[s << 3]);
        }
        __syncthreads();
#pragma unroll
        for (int ks = 0; ks < 2; ++ks) {
            f16x8 af[4], bf[4];
#pragma unroll
            for (int i = 0; i < 4; ++i) {
                const int r = wm*64 + i*16 + l15;
                af[i] = *(const f16x8*)&As[(r << 6) + ((((ks<<2)+quad) ^ (l15 & 7)) << 3)];
            }
#pragma unroll
            for (int j = 0; j < 4; ++j) {
                const int r = wn*64 + j*16 + l15;
                bf[j] = *(const f16x8*)&Bs[(r << 6) + ((((ks<<2)+quad) ^ (l15 & 7)) << 3)];
            }
#pragma unroll
            for (int i = 0; i < 4; ++i)
#pragma unroll
                for (int j = 0; j < 4; ++j)
                    acc[i][j] = MFMA16(af[i], bf[j], acc[i][j]);
        }
    }

    const int nb    = n0 + wn * 64;
    const int which = nb >> 10;
    const int h     = (nb & 1023) >> 6;
    const float gs   = 1.f / (1.f + __expf(-gates[h] * imp[h]));
    float scale = (gs > thr[0]) ? 1.f : 0.f;
    if (which == 0) scale *= LOG2E;
    f16* __restrict__ dst = (which == 0) ? q16 : ((which == 1) ? k16 : v16);
    float bv[4];
#pragma unroll
    for (int j = 0; j < 4; ++j) bv[j] = bias[nb + j*16 + l15];
#pragma unroll
    for (int i = 0; i < 4; ++i) {
#pragma unroll
        for (int reg = 0; reg < 4; ++reg) {
            const int m = m0 + wm*64 + i*16 + quad*4 + reg;
            const int b = m >> 11, s = m & (SS - 1);
            f16* rowp = dst + (((size_t)(b*HH + h))*SS + s)*DD_ + l15;
#pragma unroll
            for (int j = 0; j < 4; ++j)
                rowp[j*16] = (f16)((acc[i][j][reg] + bv[j]) * scale);
        }
    }
}

// ---------------------------------------------------------------------------
// v transpose [B,H,S,D] -> [B,H,D,S] f16, + vmean (fp32 atomic partials)
// ---------------------------------------------------------------------------
__global__ __launch_bounds__(256) void vtrans_kernel(
    const f16* __restrict__ v16, f16* __restrict__ vt, float* __restrict__ vmean)
{
    __shared__ f16 T[64][74];
    const int tid = threadIdx.x;
    const int bh = blockIdx.y, s0 = blockIdx.x << 6;
#pragma unroll
    for (int u = 0; u < 2; ++u) {
        const int f = tid + (u << 8);
        const int r = f >> 3, c = (f & 7) << 3;
        *(f16x8*)&T[r][c] = *(const f16x8*)(v16 + ((size_t)bh*SS + s0 + r)*DD_ + c);
    }
    __syncthreads();
    const int d = tid >> 2, ch = (tid & 3) << 4;
    union { f16 h[16]; f16x8 v8[2]; } t;
    float ps = 0.f;
#pragma unroll
    for (int u = 0; u < 16; ++u) { f16 val = T[ch + u][d]; t.h[u] = val; ps += (float)val; }
    f16* dp = vt + ((size_t)bh*DD_ + d)*SS + s0 + ch;
    *(f16x8*)(dp)     = t.v8[0];
    *(f16x8*)(dp + 8) = t.v8[1];
    ps += __shfl_xor(ps, 1, 64);
    ps += __shfl_xor(ps, 2, 64);
    if ((tid & 3) == 0) atomicAdd(vmean + bh*DD_ + d, ps * (1.f / SS));
}

// ---------------------------------------------------------------------------
// Flash attention v3: 1-wave (64-thr) blocks, 64 q-rows/wave (n=2 chunks of
// 32), 32x32x16 MFMA, base-2 softmax with wave-uniform running max.
// S^T = K*Q^T; P^T re-shaped to PV B-operand IN REGISTERS (shfl_xor pairs,
// no LDS); PV computes O^T = V^T * P^T so each lane owns its q-row's column
// (no epilogue broadcasts). K/V staged in private 16KB LDS via gload16.
// Grid 1024 = 32 q-chunks x 32 bh, XCD-swizzled for K/V L2 locality.
// ---------------------------------------------------------------------------
__global__ __launch_bounds__(64, 2) void attn_kernel(
    const f16* __restrict__ q16, const f16* __restrict__ k16,
    const f16* __restrict__ vt, const float* __restrict__ vmean,
    f16* __restrict__ aout)
{
    __shared__ f16 Ks[64*64];          // [key][d], swizzled 16B chunks
    __shared__ f16 Vs[64*64];          // [d][key], swizzled
    const int lane = threadIdx.x;      // 0..63
    const int l31 = lane & 31, hi = lane >> 5, l7 = lane & 7;

    // XCD swizzle: 4 heads per XCD so K/V working set (2MB) fits its L2
    const int id  = blockIdx.x;
    const int xcd = id & 7, lid = id >> 3;
    const int bh  = (xcd << 2) | (lid & 3);
    const int q0  = (lid >> 2) << 6;   // 64 q-rows per block

    const f16* qb = q16 + (size_t)bh * SS * DD_;
    const f16* kb = k16 + (size_t)bh * SS * DD_;
    const f16* vb = vt  + (size_t)bh * DD_ * SS;

    // Q frags (B-operand): B[k=ks*16+hi*8+j][n=qrow=l31], chunk n
    f16x8 qf[2][4];
#pragma unroll
    for (int n = 0; n < 2; ++n)
#pragma unroll
        for (int ks = 0; ks < 4; ++ks)
            qf[n][ks] = *(const f16x8*)(qb + (size_t)(q0 + n*32 + l31)*DD_ + ks*16 + hi*8);

    f32x16 accO[2][2];                 // [n][dt] O^T accum, C-layout col=qrow
#pragma unroll
    for (int n = 0; n < 2; ++n)
#pragma unroll
        for (int dt = 0; dt < 2; ++dt)
#pragma unroll
            for (int r = 0; r < 16; ++r) accO[n][dt][r] = 0.f;
    float M = -1.0e30f;
    float lsum[2] = {0.f, 0.f};

    for (int kt = 0; kt < SS; kt += 64) {
        __syncthreads();
        // stage 64x64 K tile and V^T tile (8 instrs each, swizzled source)
#pragma unroll
        for (int u = 0; u < 8; ++u) {
            const int r = (u << 3) + (lane >> 3);
            const int sc = ((lane & 7) ^ (r & 7)) << 3;
            gload16(kb + (size_t)(kt + r)*DD_ + sc, &Ks[(u << 9) + (lane << 3)]);
            gload16(vb + (size_t)r*SS + kt + sc,    &Vs[(u << 9) + (lane << 3)]);
        }
        __syncthreads();

        // S^T[key][qrow]: A = K rows, B = Q^T (kf reused across n)
        f32x16 accS[2][2];
#pragma unroll
        for (int n = 0; n < 2; ++n)
#pragma unroll
            for (int mt = 0; mt < 2; ++mt)
#pragma unroll
                for (int r = 0; r < 16; ++r) accS[n][mt][r] = 0.f;
#pragma unroll
        for (int ks = 0; ks < 4; ++ks)
#pragma unroll
            for (int mt = 0; mt < 2; ++mt) {
                f16x8 kf = *(const f16x8*)&Ks[((mt*32 + l31) << 6) +
                                              ((((ks<<1)+hi) ^ l7) << 3)];
#pragma unroll
                for (int n = 0; n < 2; ++n)
                    accS[n][mt] = MFMA32(kf, qf[n][ks], accS[n][mt]);
            }

        // wave-uniform tile max over both chunks
        float mx = -1.0e30f;
#pragma unroll
        for (int n = 0; n < 2; ++n)
#pragma unroll
            for (int mt = 0; mt < 2; ++mt)
#pragma unroll
                for (int r = 0; r < 16; ++r) mx = fmaxf(mx, accS[n][mt][r]);
        mx = fmaxf(mx, __shfl_xor(mx, 1, 64));
        mx = fmaxf(mx, __shfl_xor(mx, 2, 64));
        mx = fmaxf(mx, __shfl_xor(mx, 4, 64));
        mx = fmaxf(mx, __shfl_xor(mx, 8, 64));
        mx = fmaxf(mx, __shfl_xor(mx, 16, 64));
        mx = fmaxf(mx, __shfl_xor(mx, 32, 64));
        const float mnew = fmaxf(M, mx);
        const float alpha = EXP2F(M - mnew);
        M = mnew;
#pragma unroll
        for (int n = 0; n < 2; ++n) {
            lsum[n] *= alpha;
#pragma unroll
            for (int r = 0; r < 16; ++r) { accO[n][0][r] *= alpha; accO[n][1][r] *= alpha; }
        }

        // p = exp2(s - M); per-row sums (lane owns qrow col)
#pragma unroll
        for (int n = 0; n < 2; ++n) {
            float sum = 0.f;
#pragma unroll
            for (int mt = 0; mt < 2; ++mt)
#pragma unroll
                for (int r = 0; r < 16; ++r) {
                    float p = EXP2F(accS[n][mt][r] - mnew);
                    accS[n][mt][r] = p; sum += p;
                }
            sum += __shfl_xor(sum, 32, 64);
            lsum[n] += sum;
        }

        // pack P to f16x2 pairs (as ints for shuffling)
        int pki[2][2][8];
#pragma unroll
        for (int n = 0; n < 2; ++n)
#pragma unroll
            for (int mt = 0; mt < 2; ++mt)
#pragma unroll
                for (int t = 0; t < 8; ++t) {
                    union { fp16x2 h; int i; } c;
                    c.h = __builtin_amdgcn_cvt_pkrtz(accS[n][mt][2*t], accS[n][mt][2*t+1]);
                    pki[n][mt][t] = c.i;
                }

        // PV: O^T = V^T * P^T. B-frag(ks): j0-3 from h0-lane regs
        // [(2*(ks&1)+own_hi)*4 ..+4), j4-7 same regs from h1-lane.
#pragma unroll
        for (int ks = 0; ks < 4; ++ks) {
            const int mt = ks >> 1;
            const int bidx = (ks & 1) << 2;    // pair-group base: 0 or 4
            f16x8 pf[2];
#pragma unroll
            for (int n = 0; n < 2; ++n) {
                const int a0 = pki[n][mt][bidx+0], a1 = pki[n][mt][bidx+1]; // grp lo
                const int b0 = pki[n][mt][bidx+2], b1 = pki[n][mt][bidx+3]; // grp hi
                const int s0 = hi ? a0 : b0;       // what partner needs
                const int s1 = hi ? a1 : b1;
                const int r0 = __shfl_xor(s0, 32, 64);
                const int r1 = __shfl_xor(s1, 32, 64);
                union { int i[4]; f16x8 h; } u;
                u.i[0] = hi ? r0 : a0;             // j0-3: h0-lane's group
                u.i[1] = hi ? r1 : a1;
                u.i[2] = hi ? b0 : r0;             // j4-7: h1-lane's group
                u.i[3] = hi ? b1 : r1;
                pf[n] = u.h;
            }
#pragma unroll
            for (int dt = 0; dt < 2; ++dt) {
                f16x8 vf = *(const f16x8*)&Vs[((dt*32 + l31) << 6) +
                                              ((((ks<<1)+hi) ^ l7) << 3)];
#pragma unroll
                for (int n = 0; n < 2; ++n)
                    accO[n][dt] = MFMA32(vf, pf[n], accO[n][dt]);
            }
        }
    }

    // epilogue: lane owns qrow col -> per-lane 1/lsum, no shuffles.
    // O^T row = d = dt*32 + 8g + 4hi + (reg&3)
    const int b = bh >> 4, h = bh & (HH - 1);
#pragma unroll
    for (int n = 0; n < 2; ++n) {
        const float inv = 1.f / lsum[n];
        const int s = q0 + n*32 + l31;
        f16* op = aout + ((size_t)(b*SS + s))*EE + h*DD_;
#pragma unroll
        for (int dt = 0; dt < 2; ++dt)
#pragma unroll
            for (int g = 0; g < 4; ++g) {
                const int d0 = dt*32 + 8*g + 4*hi;
                float4 vm = *(const float4*)(vmean + bh*DD_ + d0);
                f16x4 o = { (f16)(accO[n][dt][4*g+0]*inv + vm.x),
                            (f16)(accO[n][dt][4*g+1]*inv + vm.y),
                            (f16)(accO[n][dt][4*g+2]*inv + vm.z),
                            (f16)(accO[n][dt][4*g+3]*inv + vm.w) };
                *(f16x4*)(op + d0) = o;
            }
    }
}

// ---------------------------------------------------------------------------
// Output GEMM, f16 MFMA, global_load_lds + swizzle: y = a@w^T + b (fp32 out)
// ---------------------------------------------------------------------------
__global__ __launch_bounds__(256) void out_gemm_kernel(
    const f16* __restrict__ a, const f16* __restrict__ w,
    const float* __restrict__ bias, float* __restrict__ y)
{
    __shared__ f16 As[128*64];
    __shared__ f16 Bs[128*64];
    const int tid  = threadIdx.x;
    const int wave = tid >> 6, lane = tid & 63;
    const int quad = lane >> 4, l15 = lane & 15;
    const int wm = wave & 1, wn = wave >> 1;
    const int m0 = blockIdx.y << 7, n0 = blockIdx.x << 7;

    f32x4 acc[4][4];
#pragma unroll
    for (int i = 0; i < 4; ++i)
#pragma unroll
        for (int j = 0; j < 4; ++j) acc[i][j] = (f32x4){0.f,0.f,0.f,0.f};

    for (int k0 = 0; k0 < EE; k0 += 64) {
        __syncthreads();
#pragma unroll
        for (int u = 0; u < 4; ++u) {
            const int s = tid + (u << 8);
            const int r = s >> 3;
            const int sc = ((s & 7) ^ (r & 7)) << 3;
            gload16(a + (size_t)(m0 + r)*EE + k0 + sc, &As[s << 3]);
            gload16(w + (size_t)(n0 + r)*EE + k0 + sc, &Bs[s << 3]);
        }
        __syncthreads();
#pragma unroll
        for (int ks = 0; ks < 2; ++ks) {
            f16x8 af[4], bf[4];
#pragma unroll
            for (int i = 0; i < 4; ++i) {
                const int r = wm*64 + i*16 + l15;
                af[i] = *(const f16x8*)&As[(r << 6) + ((((ks<<2)+quad) ^ (l15 & 7)) << 3)];
            }
#pragma unroll
            for (int j = 0; j < 4; ++j) {
                const int r = wn*64 + j*16 + l15;
                bf[j] = *(const f16x8*)&Bs[(r << 6) + ((((ks<<2)+quad) ^ (l15 & 7)) << 3)];
            }
#pragma unroll
            for (int i = 0; i < 4; ++i)
#pragma unroll
                for (int j = 0; j < 4; ++j)
                    acc[i][j] = MFMA16(af[i], bf[j], acc[i][j]);
        }
    }

    float bv[4];
#pragma unroll
    for (int j = 0; j < 4; ++j) bv[j] = bias[n0 + wn*64 + j*16 + l15];
#pragma unroll
    for (int i = 0; i < 4; ++i) {
#pragma unroll
        for (int reg = 0; reg < 4; ++reg) {
            const int m = m0 + wm*64 + i*16 + quad*4 + reg;
#pragma unroll
            for (int j = 0; j < 4; ++j)
                y[(size_t)m*EE + n0 + wn*64 + j*16 + l15] = acc[i][j][reg] + bv[j];
        }
    }
}

// ---------------------------------------------------------------------------
extern "C" void kernel_launch(void* const* d_in, const int* in_sizes, int n_in,
                              void* d_out, int out_size, void* d_ws, size_t ws_size,
                              hipStream_t stream)
{
    const float* x      = (const float*)d_in[0];
    const float* qkv_w  = (const float*)d_in[1];
    const float* qkv_b  = (const float*)d_in[2];
    const float* out_w  = (const float*)d_in[3];
    const float* out_b  = (const float*)d_in[4];
    const float* gates  = (const float*)d_in[5];
    const float* imp    = (const float*)d_in[6];
    const float* thr    = (const float*)d_in[7];
    float* out = (float*)d_out;

    const size_t TSZ = (size_t)BH * SS * DD_;
    f16* x16  = (f16*)d_ws;
    f16* w116 = x16 + (size_t)MROWS * EE;
    f16* w216 = w116 + (size_t)NQKV * EE;
    f16* q16  = w216 + (size_t)EE * EE;
    f16* k16  = q16 + TSZ;
    f16* v16  = k16 + TSZ;
    f16* vtb  = v16 + TSZ;
    f16* aout = vtb + TSZ;
    float* vmean = (float*)(aout + TSZ);

    (void)hipMemsetAsync(vmean, 0, (size_t)BH * DD_ * sizeof(float), stream);

    cvt_kernel<<<(NX4 + NW14 + NW24) / 256, 256, 0, stream>>>(
        x, qkv_w, out_w, x16, w116, w216);

    dim3 g1(NQKV/128, MROWS/128);   // 24 x 32
    qkv_gemm_kernel<<<g1, 256, 0, stream>>>(x16, w116, qkv_b, gates, imp, thr,
                                            q16, k16, v16);
    dim3 g2(SS/64, BH);             // 32 x 32
    vtrans_kernel<<<g2, 256, 0, stream>>>(v16, vtb, vmean);
    attn_kernel<<<1024, 64, 0, stream>>>(q16, k16, vtb, vmean, aout);
    dim3 g3(EE/128, MROWS/128);     // 8 x 32
    out_gemm_kernel<<<g3, 256, 0, stream>>>(aout, w216, out_b, out);
}